// Round 2
// baseline (276.784 us; speedup 1.0000x reference)
//
#include <hip/hip_runtime.h>
#include <cstdint>
#include <cstddef>

// Problem constants
#define BB 8
#define SS 2048
#define DD 512

typedef __attribute__((ext_vector_type(8))) short bf16x8;
typedef __attribute__((ext_vector_type(4))) float f32x4;

__device__ __forceinline__ unsigned short f2bf(float f) {
  unsigned int u = __builtin_bit_cast(unsigned int, f);
  u = (u + 0x7FFFu + ((u >> 16) & 1u)) >> 16;  // RNE
  return (unsigned short)u;
}
__device__ __forceinline__ float bf2f(unsigned short s) {
  return __builtin_bit_cast(float, ((unsigned int)s) << 16);
}

__device__ __forceinline__ void gload_lds16(const unsigned short* g, unsigned short* l) {
  __builtin_amdgcn_global_load_lds(
      (const __attribute__((address_space(1))) void*)g,
      (__attribute__((address_space(3))) void*)l, 16, 0, 0);
}

// ---------------------------------------------------------------------------
// 128x128-tile bf16 GEMM mainloop (m97 structure).
// A[M,K] row-major (K contiguous), B[N,K] row-major (K contiguous) = B^T input.
// 256 threads = 4 waves arranged 2x2; each wave computes a 64x64 sub-tile
// as 4x4 fragments of 16x16. BK=32 (one mfma_16x16x32 per fragment pair).
// LDS double-buffered, staged with global_load_lds width=16 (lane-linear dest).
// ---------------------------------------------------------------------------
__device__ __forceinline__ void gemm_tile(
    const unsigned short* __restrict__ A,
    const unsigned short* __restrict__ B,
    int K, unsigned short* lA, unsigned short* lB,
    f32x4 acc[4][4], size_t m0, size_t n0)
{
  const int t = threadIdx.x;
  const int l = t & 63;
  const int w = t >> 6;
  const int wr = w >> 1, wc = w & 1;
  const size_t K64 = (size_t)K * 64;

  // staging: round r covers rows r*64 + (t>>2), k-chunk (t&3)*8; LDS off = r*2048 + t*8
  const unsigned short* gA = A + (m0 + (size_t)(t >> 2)) * (size_t)K + (size_t)((t & 3) * 8);
  const unsigned short* gB = B + (n0 + (size_t)(t >> 2)) * (size_t)K + (size_t)((t & 3) * 8);

  // fragment read offsets (elements) inside a 128x32 LDS tile
  const int ar = (wr * 64 + (l & 15)) * 32 + (l >> 4) * 8;
  const int br = (wc * 64 + (l & 15)) * 32 + (l >> 4) * 8;

  const int nk = K >> 5;
  int buf = 0;

  // prologue: stage k-tile 0 into buffer 0
  gload_lds16(gA, lA + t * 8);
  gload_lds16(gA + K64, lA + 2048 + t * 8);
  gload_lds16(gB, lB + t * 8);
  gload_lds16(gB + K64, lB + 2048 + t * 8);

  for (int kt = 0; kt < nk; ++kt) {
    __syncthreads();  // stage(kt) complete (compiler drains vmcnt before barrier)
    if (kt + 1 < nk) {
      const int ko = (kt + 1) << 5;
      const int lo = (buf ^ 1) * 4096;
      gload_lds16(gA + ko, lA + lo + t * 8);
      gload_lds16(gA + ko + K64, lA + lo + 2048 + t * 8);
      gload_lds16(gB + ko, lB + lo + t * 8);
      gload_lds16(gB + ko + K64, lB + lo + 2048 + t * 8);
    }
    const unsigned short* pa = lA + buf * 4096 + ar;
    const unsigned short* pb = lB + buf * 4096 + br;
    bf16x8 af[4], bfr[4];
#pragma unroll
    for (int m = 0; m < 4; ++m) af[m] = *(const bf16x8*)(pa + m * 512);
#pragma unroll
    for (int n = 0; n < 4; ++n) bfr[n] = *(const bf16x8*)(pb + n * 512);
#pragma unroll
    for (int m = 0; m < 4; ++m)
#pragma unroll
      for (int n = 0; n < 4; ++n)
        acc[m][n] = __builtin_amdgcn_mfma_f32_16x16x32_bf16(af[m], bfr[n], acc[m][n], 0, 0, 0);
    buf ^= 1;
  }
}

// ---------------------------------------------------------------------------
// Kernel 1: convert X (8.39M f32) and Wq|Wk|Wv (3 x 262144 f32) to bf16 in ws.
// ---------------------------------------------------------------------------
__global__ __launch_bounds__(256) void convert_k(
    const float* __restrict__ X, const float* __restrict__ Wq,
    const float* __restrict__ Wk, const float* __restrict__ Wv,
    unsigned short* __restrict__ dst)
{
  const size_t NXe = (size_t)BB * SS * DD;  // 8388608
  const size_t NWe = (size_t)DD * DD;       // 262144
  size_t i = ((size_t)blockIdx.x * 256 + threadIdx.x) * 4;
  const float* src;
  size_t off;
  if (i < NXe)                { src = X;  off = i; }
  else if (i < NXe + NWe)     { src = Wq; off = i - NXe; }
  else if (i < NXe + 2 * NWe) { src = Wk; off = i - NXe - NWe; }
  else                        { src = Wv; off = i - NXe - 2 * NWe; }
  float4 f = *(const float4*)(src + off);
  ushort4 o;
  o.x = f2bf(f.x); o.y = f2bf(f.y); o.z = f2bf(f.z); o.w = f2bf(f.w);
  *(ushort4*)(dst + i) = o;
}

// ---------------------------------------------------------------------------
// Kernel 2: QKV projections. z=0 -> Q [16384,512], z=1 -> K [16384,512],
// z=2 -> V written transposed per batch: Vt[b][d][s] (so PV gets B^T layout).
// ---------------------------------------------------------------------------
__global__ __launch_bounds__(256, 2) void qkv_gemm_k(
    const unsigned short* __restrict__ Xb,
    const unsigned short* __restrict__ Wall,
    unsigned short* __restrict__ Qb,
    unsigned short* __restrict__ Kb,
    unsigned short* __restrict__ Vtb)
{
  __shared__ __align__(16) unsigned short lA[8192];
  __shared__ __align__(16) unsigned short lB[8192];
  const int z = blockIdx.z;
  const unsigned short* Bw = Wall + (size_t)z * (DD * DD);
  const size_t m0 = (size_t)blockIdx.y * 128;
  const size_t n0 = (size_t)blockIdx.x * 128;
  f32x4 acc[4][4];
#pragma unroll
  for (int m = 0; m < 4; ++m)
#pragma unroll
    for (int n = 0; n < 4; ++n) acc[m][n] = (f32x4){0.f, 0.f, 0.f, 0.f};

  gemm_tile(Xb, Bw, DD, lA, lB, acc, m0, n0);

  const int t = threadIdx.x, l = t & 63, w = t >> 6, wr = w >> 1, wc = w & 1;
  const size_t rb = m0 + (size_t)(wr * 64 + ((l >> 4) * 4));
  const int cb = (int)n0 + wc * 64 + (l & 15);
  if (z < 2) {
    unsigned short* O = z ? Kb : Qb;
#pragma unroll
    for (int m = 0; m < 4; ++m)
#pragma unroll
      for (int n = 0; n < 4; ++n)
#pragma unroll
        for (int j = 0; j < 4; ++j) {
          size_t r = rb + (size_t)(m * 16 + j);
          O[r * DD + (size_t)(cb + n * 16)] = f2bf(acc[m][n][j]);
        }
  } else {
#pragma unroll
    for (int m = 0; m < 4; ++m)
#pragma unroll
      for (int n = 0; n < 4; ++n)
#pragma unroll
        for (int j = 0; j < 4; ++j) {
          size_t r = rb + (size_t)(m * 16 + j);
          size_t bb = r >> 11, s = r & 2047;
          Vtb[((bb * DD + (size_t)(cb + n * 16)) << 11) + s] = f2bf(acc[m][n][j]);
        }
  }
}

// ---------------------------------------------------------------------------
// Kernel 3: scores = Q_b · K_b^T (raw, unscaled) -> bf16 [b][2048][2048]
// ---------------------------------------------------------------------------
__global__ __launch_bounds__(256, 2) void scores_gemm_k(
    const unsigned short* __restrict__ Qb,
    const unsigned short* __restrict__ Kb,
    unsigned short* __restrict__ Sc)
{
  __shared__ __align__(16) unsigned short lA[8192];
  __shared__ __align__(16) unsigned short lB[8192];
  const int b = blockIdx.z;
  const unsigned short* A  = Qb + (size_t)b * (SS * DD);
  const unsigned short* Bp = Kb + (size_t)b * (SS * DD);
  unsigned short* C = Sc + (size_t)b * ((size_t)SS * SS);
  const size_t m0 = (size_t)blockIdx.y * 128;
  const size_t n0 = (size_t)blockIdx.x * 128;
  f32x4 acc[4][4];
#pragma unroll
  for (int m = 0; m < 4; ++m)
#pragma unroll
    for (int n = 0; n < 4; ++n) acc[m][n] = (f32x4){0.f, 0.f, 0.f, 0.f};

  gemm_tile(A, Bp, DD, lA, lB, acc, m0, n0);

  const int t = threadIdx.x, l = t & 63, w = t >> 6, wr = w >> 1, wc = w & 1;
  const size_t rb = m0 + (size_t)(wr * 64 + ((l >> 4) * 4));
  const int cb = (int)n0 + wc * 64 + (l & 15);
#pragma unroll
  for (int m = 0; m < 4; ++m)
#pragma unroll
    for (int n = 0; n < 4; ++n)
#pragma unroll
      for (int j = 0; j < 4; ++j) {
        size_t r = rb + (size_t)(m * 16 + j);
        C[r * SS + (size_t)(cb + n * 16)] = f2bf(acc[m][n][j]);
      }
}

// ---------------------------------------------------------------------------
// Kernel 4: in-place masked softmax over each score row (scale 1/sqrt(S)).
// One block (256 threads, 4 waves) per row; 8 elements/thread.
// ---------------------------------------------------------------------------
__global__ __launch_bounds__(256) void softmax_k(
    unsigned short* __restrict__ Sc, const int* __restrict__ mask)
{
  __shared__ float smax[4], ssum[4];
  const int row = blockIdx.x;          // 0..16383
  const int b = row >> 11;
  unsigned short* p = Sc + (size_t)row * SS;
  const int* mk = mask + ((size_t)b << 11);
  const int t = threadIdx.x;
  const int c0 = t * 8;

  bf16x8 sv = *(const bf16x8*)(p + c0);
  int4 ma = *(const int4*)(mk + c0);
  int4 mb = *(const int4*)(mk + c0 + 4);
  int mm[8] = {ma.x, ma.y, ma.z, ma.w, mb.x, mb.y, mb.z, mb.w};
  const float SCALE = 0.022097086912079608f;  // 1/sqrt(2048)
  float v[8];
#pragma unroll
  for (int j = 0; j < 8; ++j) v[j] = bf2f((unsigned short)sv[j]) * SCALE;

  float mx = -3.0e38f;
#pragma unroll
  for (int j = 0; j < 8; ++j) if (mm[j]) mx = fmaxf(mx, v[j]);
#pragma unroll
  for (int off = 32; off >= 1; off >>= 1) mx = fmaxf(mx, __shfl_xor(mx, off));
  const int wid = t >> 6, ln = t & 63;
  if (ln == 0) smax[wid] = mx;
  __syncthreads();
  mx = fmaxf(fmaxf(smax[0], smax[1]), fmaxf(smax[2], smax[3]));

  float e[8];
  float sum = 0.f;
#pragma unroll
  for (int j = 0; j < 8; ++j) { e[j] = mm[j] ? __expf(v[j] - mx) : 0.f; sum += e[j]; }
#pragma unroll
  for (int off = 32; off >= 1; off >>= 1) sum += __shfl_xor(sum, off);
  if (ln == 0) ssum[wid] = sum;
  __syncthreads();
  sum = ssum[0] + ssum[1] + ssum[2] + ssum[3];
  const float inv = 1.f / sum;

  bf16x8 ov;
#pragma unroll
  for (int j = 0; j < 8; ++j) ov[j] = (short)f2bf(e[j] * inv);
  *(bf16x8*)(p + c0) = ov;
}

// ---------------------------------------------------------------------------
// Kernel 5: Out_b = P_b · V_b  (A = probs [2048,2048] bf16 k-contig,
// B = Vt [512,2048] bf16 k-contig), fp32 output straight to d_out.
// ---------------------------------------------------------------------------
__global__ __launch_bounds__(256, 2) void pv_gemm_k(
    const unsigned short* __restrict__ Sc,
    const unsigned short* __restrict__ Vtb,
    float* __restrict__ Out)
{
  __shared__ __align__(16) unsigned short lA[8192];
  __shared__ __align__(16) unsigned short lB[8192];
  const int b = blockIdx.z;
  const unsigned short* A  = Sc + (size_t)b * ((size_t)SS * SS);
  const unsigned short* Bp = Vtb + (size_t)b * (DD * SS);
  float* C = Out + (size_t)b * (SS * DD);
  const size_t m0 = (size_t)blockIdx.y * 128;
  const size_t n0 = (size_t)blockIdx.x * 128;
  f32x4 acc[4][4];
#pragma unroll
  for (int m = 0; m < 4; ++m)
#pragma unroll
    for (int n = 0; n < 4; ++n) acc[m][n] = (f32x4){0.f, 0.f, 0.f, 0.f};

  gemm_tile(A, Bp, SS, lA, lB, acc, m0, n0);

  const int t = threadIdx.x, l = t & 63, w = t >> 6, wr = w >> 1, wc = w & 1;
  const size_t rb = m0 + (size_t)(wr * 64 + ((l >> 4) * 4));
  const int cb = (int)n0 + wc * 64 + (l & 15);
#pragma unroll
  for (int m = 0; m < 4; ++m)
#pragma unroll
    for (int n = 0; n < 4; ++n)
#pragma unroll
      for (int j = 0; j < 4; ++j) {
        size_t r = rb + (size_t)(m * 16 + j);
        C[r * DD + (size_t)(cb + n * 16)] = acc[m][n][j];
      }
}

// ---------------------------------------------------------------------------
// Workspace layout (ushort elements):
//   Xb   @ 0         : 8388608   (bf16 X)
//   Wall @ 8388608   : 786432    (bf16 Wq|Wk|Wv)
//   Qb   @ 9175040   : 8388608
//   Kb   @ 17563648  : 8388608
//   Vtb  @ 25952256  : 8388608   ([b][d][s])
//   Sc   @ 34340864  : 33554432  (scores -> probs, in place)
// total = 67895296 ushorts = 135,790,592 bytes
// ---------------------------------------------------------------------------
extern "C" void kernel_launch(void* const* d_in, const int* in_sizes, int n_in,
                              void* d_out, int out_size, void* d_ws, size_t ws_size,
                              hipStream_t stream) {
  const float* X    = (const float*)d_in[0];
  const int*   mask = (const int*)d_in[1];
  const float* Wq   = (const float*)d_in[2];
  const float* Wk   = (const float*)d_in[3];
  const float* Wv   = (const float*)d_in[4];

  unsigned short* ws  = (unsigned short*)d_ws;
  unsigned short* Xb   = ws;
  unsigned short* Wall = ws + 8388608;
  unsigned short* Qb   = ws + 9175040;
  unsigned short* Kb   = ws + 17563648;
  unsigned short* Vtb  = ws + 25952256;
  unsigned short* Sc   = ws + 34340864;
  float* Out = (float*)d_out;

  // 1) fp32 -> bf16 conversion of X and the three weight matrices
  convert_k<<<8960, 256, 0, stream>>>(X, Wq, Wk, Wv, ws);

  // 2) Q/K/V projections (z = 0/1/2)
  qkv_gemm_k<<<dim3(4, 128, 3), 256, 0, stream>>>(Xb, Wall, Qb, Kb, Vtb);

  // 3) raw scores per batch
  scores_gemm_k<<<dim3(16, 16, 8), 256, 0, stream>>>(Qb, Kb, Sc);

  // 4) masked, scaled softmax in place
  softmax_k<<<16384, 256, 0, stream>>>(Sc, mask);

  // 5) probs · V -> fp32 output
  pv_gemm_k<<<dim3(4, 16, 8), 256, 0, stream>>>(Sc, Vtb, Out);
}